// Round 8
// baseline (137.123 us; speedup 1.0000x reference)
//
#include <hip/hip_runtime.h>
#include <math.h>

#define DD 64
#define NN 512
#define LL 1024
#define EPSF 1e-5f
#define NCH 32   // n-chunks (xbar partials per l)

typedef short short8 __attribute__((ext_vector_type(8)));
typedef float f32x4 __attribute__((ext_vector_type(4)));

static __device__ __forceinline__ unsigned bf16_rne(float f) {
  unsigned u = __float_as_uint(f);
  return (u + 0x7FFFu + ((u >> 16) & 1u)) >> 16;
}
static __device__ __forceinline__ float bf16_hi_f(float f) {
  unsigned u = __float_as_uint(f);
  return __uint_as_float((u + 0x7FFFu + ((u >> 16) & 1u)) & 0xFFFF0000u);
}
// HW packed convert: [bf16(a) | bf16(b)<<16]
static __device__ __forceinline__ unsigned cvt_pk_bf16(float a, float b) {
  unsigned r;
  asm("v_cvt_pk_bf16_f32 %0, %1, %2" : "=v"(r) : "v"(a), "v"(b));
  return r;
}

// ---------------------------------------------------------------------------
// Kernel W: pack Wg/Wout into MFMA B-fragment order, split bf16 hi/lo.
// Bpk short8-frag index: ((mv*2 + h)*8 + ct*2 + kt)*64 + lane
// element: col = ct*16 + (lane&15); k = kt*32 + (lane>>4)*8 + e
// ---------------------------------------------------------------------------
__global__ __launch_bounds__(256) void kW(const float* __restrict__ Wg,
                                          const float* __restrict__ Wout,
                                          unsigned* __restrict__ Bpk)
{
  const int idx = blockIdx.x * 256 + threadIdx.x;   // 0..8191
  const int e2   = idx & 3;
  const int lane = (idx >> 2) & 63;
  const int ctkt = (idx >> 8) & 7;
  const int h    = (idx >> 11) & 1;
  const int mv   = (idx >> 12) & 1;
  const int col  = ((ctkt >> 1) << 4) | (lane & 15);
  const int k0   = ((ctkt & 1) << 5) + ((lane >> 4) << 3) + (e2 << 1);
  const float* W = mv ? Wout : Wg;
  const float w0 = W[k0 * DD + col];
  const float w1 = W[(k0 + 1) * DD + col];
  unsigned b0, b1;
  if (h == 0) { b0 = bf16_rne(w0); b1 = bf16_rne(w1); }
  else        { b0 = bf16_rne(w0 - bf16_hi_f(w0)); b1 = bf16_rne(w1 - bf16_hi_f(w1)); }
  Bpk[idx] = b0 | (b1 << 16);
}

// ---------------------------------------------------------------------------
// Kernel A: as R7 + stores xn (bf16-hi) to global xnh for kC's mv1.
// block = 16 l x 16 n rows; thread = one row in regs; LN + k/v proj;
// xbar partial via butterfly + LDS combine.
// ---------------------------------------------------------------------------
__global__ __launch_bounds__(256, 4) void kA(
    const float* __restrict__ msa, const float* __restrict__ lnw, const float* __restrict__ lnb,
    const float* __restrict__ Wk, const float* __restrict__ Wv,
    float* __restrict__ kb, float* __restrict__ vb, float* __restrict__ xbarP,
    unsigned short* __restrict__ xnh)
{
  __shared__ float xc[4][16][68];
  const int t = threadIdx.x;
  const int lane = t & 63;
  const int w = t >> 6;
  const int l_loc = t & 15;
  const int n_loc = t >> 4;
  const int lt = blockIdx.x & 63;
  const int nc = blockIdx.x >> 6;
  const int l0 = lt * 16;
  const int n = nc * 16 + n_loc;
  const int l = l0 + l_loc;

  float X[DD];
  {
    const float4* rp = (const float4*)(msa + ((size_t)n * LL + l) * DD);
#pragma unroll
    for (int i = 0; i < 16; ++i) {
      const float4 f = rp[i];
      X[4*i+0] = f.x; X[4*i+1] = f.y; X[4*i+2] = f.z; X[4*i+3] = f.w;
    }
  }

  float s = 0.f, s2 = 0.f;
#pragma unroll
  for (int d = 0; d < DD; ++d) { s += X[d]; s2 = fmaf(X[d], X[d], s2); }
  const float mu = s * (1.f / DD);
  const float rs = rsqrtf(fmaf(-mu, mu, s2 * (1.f / DD)) + EPSF);

  float ka[8], va[8];
#pragma unroll
  for (int j = 0; j < 8; ++j) { ka[j] = 0.f; va[j] = 0.f; }
#pragma unroll
  for (int d = 0; d < DD; ++d) {
    const float xn = fmaf((X[d] - mu) * rs, lnw[d], lnb[d]);
    X[d] = xn;
#pragma unroll
    for (int j = 0; j < 8; ++j) {
      ka[j] = fmaf(xn, Wk[d * 8 + j], ka[j]);
      va[j] = fmaf(xn, Wv[d * 8 + j], va[j]);
    }
  }

  {
    float4* kp = (float4*)(kb + ((size_t)l * NN + n) * 8);
    float4* vp = (float4*)(vb + ((size_t)l * NN + n) * 8);
    kp[0] = make_float4(ka[0], ka[1], ka[2], ka[3]);
    kp[1] = make_float4(ka[4], ka[5], ka[6], ka[7]);
    vp[0] = make_float4(va[0], va[1], va[2], va[3]);
    vp[1] = make_float4(va[4], va[5], va[6], va[7]);
  }

  // store xn as bf16-hi (row-major, 128 B/row) BEFORE the butterfly eats X
  {
    uint4* xp = (uint4*)(xnh + ((size_t)n * LL + l) * DD);
#pragma unroll
    for (int i = 0; i < 8; ++i)
      xp[i] = make_uint4(cvt_pk_bf16(X[8*i+0], X[8*i+1]),
                         cvt_pk_bf16(X[8*i+2], X[8*i+3]),
                         cvt_pk_bf16(X[8*i+4], X[8*i+5]),
                         cvt_pk_bf16(X[8*i+6], X[8*i+7]));
  }

  {
    const bool hi1 = (lane & 16) != 0;
#pragma unroll
    for (int k = 0; k < 32; ++k) {
      const float keep = hi1 ? X[k + 32] : X[k];
      const float send = hi1 ? X[k] : X[k + 32];
      X[k] = keep + __shfl_xor(send, 16);
    }
    const bool hi2 = (lane & 32) != 0;
#pragma unroll
    for (int k = 0; k < 16; ++k) {
      const float keep = hi2 ? X[k + 16] : X[k];
      const float send = hi2 ? X[k] : X[k + 16];
      X[k] = keep + __shfl_xor(send, 32);
    }
  }
  const int d0 = ((lane >> 4) & 1) * 32 + (lane >> 5) * 16;
#pragma unroll
  for (int k = 0; k < 16; ++k) xc[w][l_loc][d0 + k] = X[k];
  __syncthreads();

#pragma unroll
  for (int j = 0; j < 4; ++j) {
    const int c = t * 4 + j;
    const int ll = c >> 6, d = c & 63;
    const float sv = xc[0][ll][d] + xc[1][ll][d] + xc[2][ll][d] + xc[3][ll][d];
    xbarP[((size_t)(l0 + ll) * NCH + nc) * DD + d] = sv;
  }
}

// ---------------------------------------------------------------------------
// Kernel B: unchanged (writes obT[d][l]).
// ---------------------------------------------------------------------------
__global__ __launch_bounds__(512) void kB(
    const float* __restrict__ kb, const float* __restrict__ vb,
    const float* __restrict__ xbarP, const float* __restrict__ Wq,
    float* __restrict__ obT)
{
  __shared__ float xbL[DD];
  __shared__ float qs[DD];
  __shared__ float ks[NN * 9];
  __shared__ float vs[NN * 9];
  const int l = blockIdx.x;
  const int t = threadIdx.x;
  const int h = t >> 6;
  const int lane = t & 63;

  const float* kl = kb + (size_t)l * NN * 8;
  const float* vl = vb + (size_t)l * NN * 8;
#pragma unroll
  for (int i = 0; i < 8; ++i) {
    const int idx = i * 512 + t;
    const int n = idx >> 3, j = idx & 7;
    ks[n*9 + j] = kl[idx];
    vs[n*9 + j] = vl[idx];
  }
  if (t < DD) {
    float s = 0.f;
    for (int p = 0; p < NCH; ++p) s += xbarP[((size_t)l * NCH + p) * DD + t];
    xbL[t] = s * (1.f / NN);
  }
  __syncthreads();
  if (t < DD) {
    float acc = 0.f;
    for (int d = 0; d < DD; ++d) acc = fmaf(xbL[d], Wq[d*DD + t], acc);
    qs[t] = acc * 0.35355339059327373f;
  }
  __syncthreads();

  float sc[8];
  float m = -1e30f;
#pragma unroll
  for (int i = 0; i < 8; ++i) {
    const int n = i * 64 + lane;
    float s = 0.f;
#pragma unroll
    for (int d = 0; d < 8; ++d) s = fmaf(qs[h*8 + d], ks[n*9 + d], s);
    sc[i] = s;
    m = fmaxf(m, s);
  }
#pragma unroll
  for (int off = 32; off; off >>= 1) m = fmaxf(m, __shfl_xor(m, off));
  float ssum = 0.f;
#pragma unroll
  for (int i = 0; i < 8; ++i) { sc[i] = __expf(sc[i] - m); ssum += sc[i]; }
#pragma unroll
  for (int off = 32; off; off >>= 1) ssum += __shfl_xor(ssum, off);
  const float inv = 1.f / ssum;

  float oacc[8];
#pragma unroll
  for (int d = 0; d < 8; ++d) oacc[d] = 0.f;
#pragma unroll
  for (int i = 0; i < 8; ++i) {
    const int n = i * 64 + lane;
#pragma unroll
    for (int d = 0; d < 8; ++d) oacc[d] = fmaf(sc[i], vs[n*9 + d], oacc[d]);
  }
#pragma unroll
  for (int d = 0; d < 8; ++d) {
#pragma unroll
    for (int off = 32; off; off >>= 1) oacc[d] += __shfl_xor(oacc[d], off);
  }
  if (lane == 0) {
#pragma unroll
    for (int d = 0; d < 8; ++d)
      obT[(size_t)(h * 8 + d) * LL + l] = oacc[d] * inv;
  }
}

// ---------------------------------------------------------------------------
// Kernel C v5: no msa read, no LN, no phase-1 LDS. mv1 A-frags gathered
// DIRECTLY from global xnh (L3-hot, 16B/lane, 2KB-contig/wave); 2-term mv1.
// sigmoid*o -> t split hi/lo via cvt_pk -> wave-private LDS -> 3-term mv2.
// Zero barriers. 128 rows/block, 4 waves; wave owns 32 rows x 64 cols.
// A-frag: lane holds row=(lane&15), k=8*(lane>>4)+e.
// C/D: reg j -> row=(lane>>4)*4+j, col=lane&15.
// ---------------------------------------------------------------------------
__global__ __launch_bounds__(256, 4) void kC(
    const unsigned short* __restrict__ xnh, const unsigned* __restrict__ Bpk,
    const float* __restrict__ bg, const float* __restrict__ obT,
    const float* __restrict__ bout, float* __restrict__ out)
{
  __shared__ unsigned short TH[128 * 72];  // 18 KB (t hi)
  __shared__ unsigned short TL[128 * 72];  // 18 KB (t lo)
  const int t = threadIdx.x;
  const int lane = t & 63;
  const int w = t >> 6;
  const int rbase = 32 * w;
  const size_t R0 = (size_t)blockIdx.x * 128;

  const short8* Bp = (const short8*)Bpk;   // frag*64 + lane

  // ---- mv1: gate pre-activation (2-term, A direct from global) ----
  f32x4 acc[2][4];
#pragma unroll
  for (int rt = 0; rt < 2; ++rt)
#pragma unroll
    for (int ct = 0; ct < 4; ++ct) acc[rt][ct] = f32x4{0.f, 0.f, 0.f, 0.f};

  {
    short8 ah[2][2];
#pragma unroll
    for (int rt = 0; rt < 2; ++rt) {
      const size_t ar = R0 + rbase + rt * 16 + (lane & 15);
      const int kg = (lane >> 4) * 8;
      ah[rt][0] = *(const short8*)&xnh[ar * DD + kg];
      ah[rt][1] = *(const short8*)&xnh[ar * DD + 32 + kg];
    }
#pragma unroll
    for (int ct = 0; ct < 4; ++ct) {
      const short8 bh0 = Bp[(0 * 8 + ct * 2 + 0) * 64 + lane];
      const short8 bh1 = Bp[(0 * 8 + ct * 2 + 1) * 64 + lane];
      const short8 bl0 = Bp[(1 * 8 + ct * 2 + 0) * 64 + lane];
      const short8 bl1 = Bp[(1 * 8 + ct * 2 + 1) * 64 + lane];
#pragma unroll
      for (int rt = 0; rt < 2; ++rt) {
        f32x4 c = acc[rt][ct];
        c = __builtin_amdgcn_mfma_f32_16x16x32_bf16(ah[rt][0], bh0, c, 0, 0, 0);
        c = __builtin_amdgcn_mfma_f32_16x16x32_bf16(ah[rt][1], bh1, c, 0, 0, 0);
        c = __builtin_amdgcn_mfma_f32_16x16x32_bf16(ah[rt][0], bl0, c, 0, 0, 0);
        c = __builtin_amdgcn_mfma_f32_16x16x32_bf16(ah[rt][1], bl1, c, 0, 0, 0);
        acc[rt][ct] = c;
      }
    }
  }

  // ---- sigmoid * o -> t, split via cvt_pk into TH/TL (wave-private) ----
#pragma unroll
  for (int rt = 0; rt < 2; ++rt) {
    const int rl0 = rbase + rt * 16 + ((lane >> 4) << 2);
    const int li0 = (int)((R0 + rl0) & (LL - 1));
#pragma unroll
    for (int ct = 0; ct < 4; ++ct) {
      const int col = ct * 16 + (lane & 15);
      const float4 ov = *(const float4*)&obT[(size_t)col * LL + li0];
      const float bgc = bg[col];
      const float p0 = acc[rt][ct][0] + bgc;
      const float p1 = acc[rt][ct][1] + bgc;
      const float p2 = acc[rt][ct][2] + bgc;
      const float p3 = acc[rt][ct][3] + bgc;
      const float tv0 = ov.x / (1.f + __expf(-p0));
      const float tv1 = ov.y / (1.f + __expf(-p1));
      const float tv2 = ov.z / (1.f + __expf(-p2));
      const float tv3 = ov.w / (1.f + __expf(-p3));
      const unsigned ph01 = cvt_pk_bf16(tv0, tv1);
      const unsigned ph23 = cvt_pk_bf16(tv2, tv3);
      const float h0 = __uint_as_float(ph01 << 16);
      const float h1 = __uint_as_float(ph01 & 0xFFFF0000u);
      const float h2 = __uint_as_float(ph23 << 16);
      const float h3 = __uint_as_float(ph23 & 0xFFFF0000u);
      const unsigned pl01 = cvt_pk_bf16(tv0 - h0, tv1 - h1);
      const unsigned pl23 = cvt_pk_bf16(tv2 - h2, tv3 - h3);
      TH[(rl0 + 0) * 72 + col] = (unsigned short)ph01;
      TH[(rl0 + 1) * 72 + col] = (unsigned short)(ph01 >> 16);
      TH[(rl0 + 2) * 72 + col] = (unsigned short)ph23;
      TH[(rl0 + 3) * 72 + col] = (unsigned short)(ph23 >> 16);
      TL[(rl0 + 0) * 72 + col] = (unsigned short)pl01;
      TL[(rl0 + 1) * 72 + col] = (unsigned short)(pl01 >> 16);
      TL[(rl0 + 2) * 72 + col] = (unsigned short)pl23;
      TL[(rl0 + 3) * 72 + col] = (unsigned short)(pl23 >> 16);
    }
  }
  // no barrier: wave-private rows

  // ---- mv2: out = t @ Wout + bout (3-term) ----
#pragma unroll
  for (int rt = 0; rt < 2; ++rt)
#pragma unroll
    for (int ct = 0; ct < 4; ++ct) {
      const float bo = bout[ct * 16 + (lane & 15)];
      acc[rt][ct] = f32x4{bo, bo, bo, bo};
    }
  {
    short8 ah[2][2], al[2][2];
#pragma unroll
    for (int rt = 0; rt < 2; ++rt) {
      const int ar = rbase + rt * 16 + (lane & 15);
      const int kg = (lane >> 4) * 8;
      ah[rt][0] = *(const short8*)&TH[ar * 72 + kg];
      ah[rt][1] = *(const short8*)&TH[ar * 72 + 32 + kg];
      al[rt][0] = *(const short8*)&TL[ar * 72 + kg];
      al[rt][1] = *(const short8*)&TL[ar * 72 + 32 + kg];
    }
#pragma unroll
    for (int ct = 0; ct < 4; ++ct) {
      const short8 bh0 = Bp[(2 * 8 + ct * 2 + 0) * 64 + lane];
      const short8 bh1 = Bp[(2 * 8 + ct * 2 + 1) * 64 + lane];
      const short8 bl0 = Bp[(3 * 8 + ct * 2 + 0) * 64 + lane];
      const short8 bl1 = Bp[(3 * 8 + ct * 2 + 1) * 64 + lane];
#pragma unroll
      for (int rt = 0; rt < 2; ++rt) {
        f32x4 c = acc[rt][ct];
        c = __builtin_amdgcn_mfma_f32_16x16x32_bf16(ah[rt][0], bh0, c, 0, 0, 0);
        c = __builtin_amdgcn_mfma_f32_16x16x32_bf16(ah[rt][1], bh1, c, 0, 0, 0);
        c = __builtin_amdgcn_mfma_f32_16x16x32_bf16(ah[rt][0], bl0, c, 0, 0, 0);
        c = __builtin_amdgcn_mfma_f32_16x16x32_bf16(ah[rt][1], bl1, c, 0, 0, 0);
        c = __builtin_amdgcn_mfma_f32_16x16x32_bf16(al[rt][0], bh0, c, 0, 0, 0);
        c = __builtin_amdgcn_mfma_f32_16x16x32_bf16(al[rt][1], bh1, c, 0, 0, 0);
        acc[rt][ct] = c;
      }
    }
  }

#pragma unroll
  for (int rt = 0; rt < 2; ++rt) {
#pragma unroll
    for (int j = 0; j < 4; ++j) {
      const size_t rg = R0 + rbase + rt * 16 + ((lane >> 4) << 2) + j;
#pragma unroll
      for (int ct = 0; ct < 4; ++ct)
        out[rg * DD + ct * 16 + (lane & 15)] = acc[rt][ct][j];
    }
  }
}

// ---------------------------------------------------------------------------
extern "C" void kernel_launch(void* const* d_in, const int* in_sizes, int n_in,
                              void* d_out, int out_size, void* d_ws, size_t ws_size,
                              hipStream_t stream)
{
  const float* msa  = (const float*)d_in[0];
  const float* lnw  = (const float*)d_in[1];
  const float* lnb  = (const float*)d_in[2];
  const float* Wq   = (const float*)d_in[3];
  const float* Wk   = (const float*)d_in[4];
  const float* Wv   = (const float*)d_in[5];
  const float* Wg   = (const float*)d_in[6];
  const float* bg   = (const float*)d_in[7];
  const float* Wout = (const float*)d_in[8];
  const float* bout = (const float*)d_in[9];
  float* out = (float*)d_out;

  float* kb    = (float*)d_ws;                        // (L, N, 8)  16 MB
  float* vb    = kb + (size_t)LL * NN * 8;            // (L, N, 8)  16 MB
  float* xbarP = vb + (size_t)LL * NN * 8;            // (L, 32, 64) 8 MB
  float* obT   = xbarP + (size_t)LL * NCH * DD;       // (64, L)   256 KB
  unsigned* Bpk = (unsigned*)(obT + (size_t)DD * LL); // 32 KB packed weights
  unsigned short* xnh = (unsigned short*)(Bpk + 8192);// (N*L, 64) bf16 64 MB

  kW<<<32, 256, 0, stream>>>(Wg, Wout, Bpk);
  kA<<<64 * NCH, 256, 0, stream>>>(msa, lnw, lnb, Wk, Wv, kb, vb, xbarP, xnh);
  kB<<<LL, 512, 0, stream>>>(kb, vb, xbarP, Wq, obT);
  kC<<<(NN * LL) / 128, 256, 0, stream>>>(xnh, Bpk, bg, obT, bout, out);
}